// Round 1
// 208.782 us; speedup vs baseline: 1.0517x; 1.0517x over previous
//
#include <hip/hip_runtime.h>
#include <stdint.h>

// Graphormer layer constants
#define NB 128   // batch
#define NN 256   // nodes
#define NE 1024  // edges
#define ND 128   // model dim
#define NH 8     // heads
#define NDK 16   // head dim
#define NEGV -9.0e15f

typedef unsigned short u16;
typedef unsigned int u32;
typedef unsigned char u8;
typedef __attribute__((ext_vector_type(8))) short short8;
typedef __attribute__((ext_vector_type(4))) float float4v;
typedef __attribute__((ext_vector_type(2))) float f32x2;

__device__ __forceinline__ float bf2f(u16 u) { return __uint_as_float(((u32)u) << 16); }
__device__ __forceinline__ u16 f2bf(float f) {
    u32 u = __float_as_uint(f);
    u += 0x7fffu + ((u >> 16) & 1u);  // round-to-nearest-even
    return (u16)(u >> 16);
}
__device__ __forceinline__ float ldf(const void* p, size_t i, int f32) {
    return f32 ? ((const float*)p)[i] : bf2f(((const u16*)p)[i]);
}
__device__ __forceinline__ void stf(void* p, size_t i, int f32, float v) {
    if (f32) ((float*)p)[i] = v;
    else ((u16*)p)[i] = f2bf(v);
}
__device__ __forceinline__ void unpack8(uint4 a, float* o) {
    o[0] = bf2f(a.x & 0xffff); o[1] = bf2f(a.x >> 16);
    o[2] = bf2f(a.y & 0xffff); o[3] = bf2f(a.y >> 16);
    o[4] = bf2f(a.z & 0xffff); o[5] = bf2f(a.z >> 16);
    o[6] = bf2f(a.w & 0xffff); o[7] = bf2f(a.w >> 16);
}
// {low bf16, high bf16} of a u32 word -> f32x2
__device__ __forceinline__ f32x2 bfpair(u32 w) {
    return (f32x2){__uint_as_float(w << 16), __uint_as_float(w & 0xffff0000u)};
}
// pack two f32 -> two bf16 (round-nearest-up; p>=0 finite)
__device__ __forceinline__ u32 pk_bf(float a, float b) {
    return ((__float_as_uint(a) + 0x8000u) >> 16) |
           ((__float_as_uint(b) + 0x8000u) & 0xffff0000u);
}
union Pack8 { u16 u[8]; u32 w[4]; short8 v; };

// ---------------------------------------------------------------------------
// Slim format probe on samples (logic verified r2-7; sampling keeps certainty:
// f32 detect P~1-0.76^16384; mask bytes 4096 cover >1000 elems).
// flags[0]: x dtype 1=f32, 0=bf16.  flags[1]: mask elem width (1/2/4 bytes).
// ---------------------------------------------------------------------------
__global__ __launch_bounds__(256) void k_detect(const u16* x16, const u8* m8, int* flags) {
    __shared__ u32 sev[256], sg1[256], smx[256];
    int tid = threadIdx.x;
    u32 ev = 0;
    for (int i = tid * 128; i < tid * 128 + 128; ++i) {
        u32 e = (x16[i] >> 7) & 0xffu;
        ev |= (e >= 0xC2u) ? 1u : 0u;
    }
    u32 g1 = 0, mx = 0;
    for (int i = 0; i < 16; ++i) {
        int idx = tid * 16 + i;
        u32 bv = m8[idx];
        if ((idx & 3) == 1) g1 |= bv;
        mx = mx > bv ? mx : bv;
    }
    sev[tid] = ev; sg1[tid] = g1; smx[tid] = mx;
    __syncthreads();
    for (int s = 128; s > 0; s >>= 1) {
        if (tid < s) {
            sev[tid] |= sev[tid + s];
            sg1[tid] |= sg1[tid + s];
            smx[tid] = smx[tid] > smx[tid + s] ? smx[tid] : smx[tid + s];
        }
        __syncthreads();
    }
    if (tid == 0) {
        flags[0] = sev[0] ? 1 : 0;
        flags[1] = (sg1[0] == 0) ? 4 : ((smx[0] <= 1u) ? 1 : 2);
    }
}

// ---------------------------------------------------------------------------
// wmean, parallel: 129 blocks x 64 lanes. Block k<128: mean_d We_w[k,d];
// block 128: mean(We_b).
// ---------------------------------------------------------------------------
__global__ __launch_bounds__(64) void k_wmean(const void* Wew, const void* Web,
                                              const int* flags, float* wmean) {
    int k = blockIdx.x, lane = threadIdx.x;
    int f32 = flags[0];
    const void* src = (k < 128) ? Wew : Web;
    size_t base = (k < 128) ? (size_t)k * ND : 0;
    float s = ldf(src, base + lane, f32) + ldf(src, base + lane + 64, f32);
#pragma unroll
    for (int off = 32; off; off >>= 1) s += __shfl_xor(s, off, 64);
    if (lane == 0) wmean[k] = s * (1.0f / ND);
}

// ---------------------------------------------------------------------------
// Edge features, saturating grid (r6-verified): 16 lanes/edge, 16 edges/block,
// 8192 blocks, one 16B load/thread. featsE in edge order.
// ---------------------------------------------------------------------------
__global__ __launch_bounds__(256) void k_efeat(const void* ea, const float* wmean,
                                               const int* flags, float* featsE) {
    __shared__ __align__(16) float swm[132];
    int tid = threadIdx.x;
    int f32 = flags[0];
    if (tid <= ND) swm[tid] = wmean[tid];
    __syncthreads();
    int sub = tid & 15, grp = tid >> 4;
    size_t eidx = (size_t)blockIdx.x * 16 + grp;
    const float4* wv = (const float4*)&swm[sub * 8];
    float4 w0 = wv[0], w1 = wv[1];
    size_t base = eidx * ND + sub * 8;
    float part;
    if (f32) {
        const float4* p = (const float4*)((const float*)ea + base);
        float4 a0 = p[0], a1 = p[1];
        part = a0.x * w0.x + a0.y * w0.y + a0.z * w0.z + a0.w * w0.w +
               a1.x * w1.x + a1.y * w1.y + a1.z * w1.z + a1.w * w1.w;
    } else {
        uint4 a = *(const uint4*)((const u16*)ea + base);
        float xv[8];
        unpack8(a, xv);
        part = xv[0] * w0.x + xv[1] * w0.y + xv[2] * w0.z + xv[3] * w0.w +
               xv[4] * w1.x + xv[5] * w1.y + xv[6] * w1.z + xv[7] * w1.w;
    }
    part += __shfl_xor(part, 1);
    part += __shfl_xor(part, 2);
    part += __shfl_xor(part, 4);
    part += __shfl_xor(part, 8);
    if (sub == 0) featsE[eidx] = part + swm[ND];
}

// ---------------------------------------------------------------------------
// Per-batch degrees + row-sorted CSR (cols,feats,rowstart). (r5/6-verified)
// ---------------------------------------------------------------------------
__global__ __launch_bounds__(256) void k_csr(const int* ei, const float* featsE,
                                             float* degr, float* degc, int* rowstartG,
                                             u16* colsG, float* featsG) {
    __shared__ int cr[NN], cc[NN], offs[NN], rs[NN + 1];
    int b = blockIdx.x, tid = threadIdx.x;
    cr[tid] = 0; cc[tid] = 0;
    __syncthreads();
    const int* rows = ei + (size_t)b * 2 * NE;   // (B,2,E)
    const int* cols = rows + NE;
    for (int e = tid; e < NE; e += 256) {
        atomicAdd(&cr[rows[e]], 1);
        atomicAdd(&cc[cols[e]], 1);
    }
    __syncthreads();
    degr[b * NN + tid] = (float)cr[tid];
    degc[b * NN + tid] = (float)cc[tid];
    if (tid == 0) {
        int a = 0;
        for (int n = 0; n < NN; ++n) { rs[n] = a; a += cr[n]; }
        rs[NN] = a;
    }
    __syncthreads();
    offs[tid] = rs[tid];
    rowstartG[b * (NN + 1) + tid] = rs[tid];
    if (tid == 0) rowstartG[b * (NN + 1) + NN] = rs[NN];
    __syncthreads();
    for (int e = tid; e < NE; e += 256) {
        int r = rows[e];
        int pos = atomicAdd(&offs[r], 1);
        colsG[(size_t)b * NE + pos] = (u16)cols[e];
        featsG[(size_t)b * NE + pos] = featsE[(size_t)b * NE + e];
    }
}

// ---------------------------------------------------------------------------
// Pack [Wq|Wk|Wv] (130x384, K padded to 160) into MFMA B-fragment order.
// (r4-verified)
// ---------------------------------------------------------------------------
__global__ __launch_bounds__(64) void k_packB(const void* Wq, const void* Wk,
                                              const void* Wv, const int* flags, u16* WP) {
    int kT = blockIdx.x / 24, nT = blockIdx.x % 24;
    int lane = threadIdx.x;
    int col = lane & 15, quad = lane >> 4;
    int n = nT * 16 + col;
    int mat = n >> 7, nm = n & 127;
    const void* W = (mat == 0) ? Wq : (mat == 1) ? Wk : Wv;
    int f32 = flags[0];
    Pack8 c;
#pragma unroll
    for (int j = 0; j < 8; ++j) {
        int k = kT * 32 + quad * 8 + j;
        c.u[j] = (k < 130) ? f2bf(ldf(W, (size_t)k * ND + nm, f32)) : (u16)0;
    }
    *(short8*)(WP + ((size_t)(kT * 24 + nT) * 64 + lane) * 8) = c.v;
}

// ---------------------------------------------------------------------------
// MFMA QKV GEMM. Q (pre-scaled by 0.25=1/sqrt(dk)), K -> [b][h][node][dk];
// V -> both row-major vw AND transposed vt [b][h][dk][node] (for PV B-frags).
// ---------------------------------------------------------------------------
__global__ __launch_bounds__(256) void k_gemm(const void* x, const float* degr,
                                              const float* degc, const u16* WP,
                                              const int* flags, u16* qw, u16* kw,
                                              u16* vw, u16* vt) {
    int tid = threadIdx.x;
    int w = tid >> 6, lane = tid & 63;
    int quad = lane >> 4, col = lane & 15;
    int m0 = blockIdx.x * 64 + w * 16;
    int row = m0 + col;
    int f32 = flags[0];

    float4v acc[24];
#pragma unroll
    for (int t = 0; t < 24; ++t) acc[t] = (float4v){0.f, 0.f, 0.f, 0.f};

    const short8* wp = (const short8*)WP;
    for (int kT = 0; kT < 5; ++kT) {
        short8 a;
        if (kT < 4) {
            if (!f32) {
                a = *(const short8*)((const u16*)x + (size_t)row * ND + kT * 32 + quad * 8);
            } else {
                const float* xf = (const float*)x + (size_t)row * ND + kT * 32 + quad * 8;
                Pack8 c;
#pragma unroll
                for (int j = 0; j < 8; ++j) c.u[j] = f2bf(xf[j]);
                a = c.v;
            }
        } else {
            Pack8 c;
#pragma unroll
            for (int j = 0; j < 8; ++j) c.u[j] = 0;
            if (quad == 0) {
                c.u[0] = f2bf(degr[row]);
                c.u[1] = f2bf(degc[row]);
            }
            a = c.v;
        }
#pragma unroll
        for (int nT = 0; nT < 24; ++nT) {
            short8 bfr = wp[(size_t)(kT * 24 + nT) * 64 + lane];
            acc[nT] = __builtin_amdgcn_mfma_f32_16x16x32_bf16(a, bfr, acc[nT], 0, 0, 0);
        }
    }
    int bb = m0 >> 8;
    int nodebase = (m0 & 255) + quad * 4;
#pragma unroll
    for (int nT = 0; nT < 16; ++nT) {  // Q (scaled), K : [node][dk]
        int h = nT & 7;
        u16* O = (nT < 8) ? qw : kw;
        float sc = (nT < 8) ? 0.25f : 1.0f;
        size_t base = ((size_t)bb * NH + h) * NN + nodebase;
#pragma unroll
        for (int reg = 0; reg < 4; ++reg)
            O[(base + reg) * NDK + col] = f2bf(acc[nT][reg] * sc);
    }
#pragma unroll
    for (int nT = 16; nT < 24; ++nT) {  // V: row-major + transposed
        int h = nT - 16;
        size_t base = ((size_t)bb * NH + h) * NN + nodebase;
#pragma unroll
        for (int reg = 0; reg < 4; ++reg)
            vw[(base + reg) * NDK + col] = f2bf(acc[nT][reg]);
        u32 lo = (u32)f2bf(acc[nT][0]) | ((u32)f2bf(acc[nT][1]) << 16);
        u32 hi = (u32)f2bf(acc[nT][2]) | ((u32)f2bf(acc[nT][3]) << 16);
        *(uint2*)(vt + (((size_t)bb * NH + h) * NDK + col) * NN + nodebase) = make_uint2(lo, hi);
    }
}

// ---------------------------------------------------------------------------
// MFMA flash attention per (h,b), 256 threads. Main loop is PURE (mask bias
// as MFMA C-init, scale pre-folded into Q, no edge work). Out scattered to
// LDS f32 (row stride 17: 17 coprime 32 -> conflict-free per-row access);
// per-query post-pass pulls the row into REGISTERS, applies sparse edge
// corrections (dl = e^{s+f}-e^s, exact under no-max softmax) in-reg, and
// writes global vectorized. cols/feats read straight from L2 (dropped LDS
// staging). LDS = 40,192 B -> 4 blocks/CU (full 1024-block grid resident in
// one round; was 3/CU = 768+256 two-round tail).
// ---------------------------------------------------------------------------
__global__ __launch_bounds__(256, 4) void k_attn(const u16* qg, const u16* kg,
                                              const u16* vw, const u16* vt,
                                              const void* mask, const int* flags,
                                              const int* rowstartG, const u16* colsG,
                                              const float* featsG, void* out) {
    __shared__ __align__(16) u16 Ks[NN][24];     // 12,288 B (stride 48B: aligned + bank-spread)
    __shared__ __align__(16) u16 Vs[NDK][264];   //  8,448 B (V^T)
    __shared__ __align__(16) float mb[NN];       //  1,024 B
    __shared__ __align__(16) float Of[NN * 17];  // 17,408 B (out accum, stride 17)
    __shared__ float lbuf[NN];                   //  1,024 B
    int h = blockIdx.x, b = blockIdx.y, tid = threadIdx.x;
    int wv = tid >> 6, lane = tid & 63;
    int col = lane & 15, g = lane >> 4;
    int f32 = flags[0], mw = flags[1];
    size_t hb = ((size_t)b * NH + h) * NN;
    // hoist CSR row extent loads (coalesced; overlap with staging+main loop)
    int e0 = rowstartG[b * (NN + 1) + tid];
    int e1 = rowstartG[b * (NN + 1) + tid + 1];
    {   // stage K rows (32B/thread, coalesced)
        const uint4* src = (const uint4*)(kg + (hb + tid) * NDK);
        uint4 a0 = src[0], a1 = src[1];
        uint4* dst = (uint4*)&Ks[tid][0];
        dst[0] = a0; dst[1] = a1;
    }
    {   // stage V^T rows
        int dk = tid >> 4, chunk = tid & 15;
        const uint4* src = (const uint4*)(vt + ((size_t)(b * NH + h) * NDK + dk) * NN + chunk * 16);
        uint4 a0 = src[0], a1 = src[1];
        uint4* dst = (uint4*)&Vs[dk][chunk * 16];
        dst[0] = a0; dst[1] = a1;
    }
    {   // mask bias
        size_t mi = (size_t)b * NN + tid;
        bool mv;
        if (mw == 4)      mv = ((const u32*)mask)[mi] != 0;
        else if (mw == 2) mv = ((const u16*)mask)[mi] != 0;
        else              mv = ((const u8*)mask)[mi] != 0;
        mb[tid] = mv ? 0.0f : NEGV;
    }
    // Q B-fragments (k=dk=8g+j zero-padded, n=q=lane&15); Q pre-scaled
    short8 qf[4];
#pragma unroll
    for (int qt = 0; qt < 4; ++qt) {
        int qtabs = wv * 4 + qt;
        short8 qv = {0, 0, 0, 0, 0, 0, 0, 0};
        if (g < 2)
            qv = *(const short8*)(qg + (hb + qtabs * 16 + col) * NDK + 8 * g);
        qf[qt] = qv;
    }
    __syncthreads();

    float4v outv[4];
    float lpart[4];
#pragma unroll
    for (int qt = 0; qt < 4; ++qt) {
        outv[qt] = (float4v){0.f, 0.f, 0.f, 0.f};
        lpart[qt] = 0.f;
    }

    for (int kt = 0; kt < 16; ++kt) {
        short8 kf = {0, 0, 0, 0, 0, 0, 0, 0};
        if (g < 2) kf = *(const short8*)&Ks[kt * 16 + col][8 * g];
        Pack8 vv;
        {
            uint2 t2 = *(const uint2*)&Vs[col][kt * 16 + 4 * g];
            vv.w[0] = t2.x; vv.w[1] = t2.y; vv.w[2] = 0; vv.w[3] = 0;
        }
        float4 mb4 = *(const float4*)&mb[kt * 16 + 4 * g];
        float4v cin = (float4v){mb4.x, mb4.y, mb4.z, mb4.w};
#pragma unroll
        for (int qt = 0; qt < 4; ++qt) {
            float4v s4 = __builtin_amdgcn_mfma_f32_16x16x32_bf16(kf, qf[qt], cin, 0, 0, 0);
            float p0 = __expf(fminf(s4[0], 60.f));
            float p1 = __expf(fminf(s4[1], 60.f));
            float p2 = __expf(fminf(s4[2], 60.f));
            float p3 = __expf(fminf(s4[3], 60.f));
            lpart[qt] += (p0 + p1) + (p2 + p3);
            Pack8 pp;
            pp.w[0] = pk_bf(p0, p1);
            pp.w[1] = pk_bf(p2, p3);
            pp.w[2] = 0; pp.w[3] = 0;
            outv[qt] = __builtin_amdgcn_mfma_f32_16x16x32_bf16(pp.v, vv.v, outv[qt], 0, 0, 0);
        }
    }
    // l reduce across g groups; scatter out to LDS (stride-17 rows)
#pragma unroll
    for (int qt = 0; qt < 4; ++qt) {
        float l = lpart[qt];
        l += __shfl_xor(l, 16);
        l += __shfl_xor(l, 32);
        if (g == 0) lbuf[(wv * 4 + qt) * 16 + col] = l;
        int q0 = (wv * 4 + qt) * 16 + 4 * g;
#pragma unroll
        for (int reg = 0; reg < 4; ++reg)
            Of[(q0 + reg) * 17 + col] = outv[qt][reg];
    }
    __syncthreads();

    // per-query edge corrections: thread tid owns q=tid (exclusive row), all
    // accumulation in registers (no LDS RMW -> no 32-way conflicts)
    float lfin = lbuf[tid];
    f32x2 r[8];
#pragma unroll
    for (int j = 0; j < 8; ++j)
        r[j] = (f32x2){Of[tid * 17 + 2 * j], Of[tid * 17 + 2 * j + 1]};
    {
        const uint4* qp = (const uint4*)(qg + (hb + tid) * NDK);
        uint4 qa_ = qp[0], qb_ = qp[1];
        f32x2 qr[8];
        qr[0] = bfpair(qa_.x); qr[1] = bfpair(qa_.y);
        qr[2] = bfpair(qa_.z); qr[3] = bfpair(qa_.w);
        qr[4] = bfpair(qb_.x); qr[5] = bfpair(qb_.y);
        qr[6] = bfpair(qb_.z); qr[7] = bfpair(qb_.w);
        for (int e = e0; e < e1; ++e) {
            int c = colsG[(size_t)b * NE + e];
            float f = featsG[(size_t)b * NE + e];
            const u32* kcw = (const u32*)&Ks[c][0];   // c*48B: 16-aligned
            f32x2 s2 = qr[0] * bfpair(kcw[0]);
            s2 += qr[1] * bfpair(kcw[1]); s2 += qr[2] * bfpair(kcw[2]);
            s2 += qr[3] * bfpair(kcw[3]); s2 += qr[4] * bfpair(kcw[4]);
            s2 += qr[5] * bfpair(kcw[5]); s2 += qr[6] * bfpair(kcw[6]);
            s2 += qr[7] * bfpair(kcw[7]);
            float s = s2.x + s2.y + mb[c];
            float dl = __expf(fminf(s + f, 60.f)) - __expf(fminf(s, 60.f));
            lfin += dl;
            const uint4* vp = (const uint4*)(vw + (hb + c) * NDK);
            uint4 v0 = vp[0], v1 = vp[1];
            f32x2 d2 = (f32x2){dl, dl};
            r[0] += d2 * bfpair(v0.x); r[1] += d2 * bfpair(v0.y);
            r[2] += d2 * bfpair(v0.z); r[3] += d2 * bfpair(v0.w);
            r[4] += d2 * bfpair(v1.x); r[5] += d2 * bfpair(v1.y);
            r[6] += d2 * bfpair(v1.z); r[7] += d2 * bfpair(v1.w);
        }
    }
    // final: own row, from registers, vectorized global write
    float inv = 1.0f / lfin;  // mask[:,0]=True -> l > 0
    size_t obase = ((size_t)(b * NN + tid)) * ND + h * NDK;
    if (f32) {
        float4* op = (float4*)((float*)out + obase);  // 64B-aligned (obase % 16 == 0)
#pragma unroll
        for (int jj = 0; jj < 4; ++jj) {
            float4 w;
            w.x = r[2 * jj].x * inv;     w.y = r[2 * jj].y * inv;
            w.z = r[2 * jj + 1].x * inv; w.w = r[2 * jj + 1].y * inv;
            op[jj] = w;
        }
    } else {
        u16* op = (u16*)out + obase;  // 32B-aligned
        Pack8 pa, pb;
#pragma unroll
        for (int jj = 0; jj < 4; ++jj) {
            pa.u[2 * jj]     = f2bf(r[jj].x * inv);
            pa.u[2 * jj + 1] = f2bf(r[jj].y * inv);
            pb.u[2 * jj]     = f2bf(r[jj + 4].x * inv);
            pb.u[2 * jj + 1] = f2bf(r[jj + 4].y * inv);
        }
        *(uint4*)op = *(uint4*)&pa.w[0];
        *(uint4*)(op + 8) = *(uint4*)&pb.w[0];
    }
}

// ---------------------------------------------------------------------------
// In-place residual + LayerNorm on d_out. One wave per row. (verified)
// ---------------------------------------------------------------------------
__global__ __launch_bounds__(256) void k_ln(void* out, const void* x, const void* g,
                                            const void* be, const int* flags) {
    int f32 = flags[0];
    int tid = threadIdx.x, wv = tid >> 6, lane = tid & 63;
    int row = blockIdx.x * 4 + wv;
    size_t base = (size_t)row * ND;
    float v0 = ldf(out, base + lane, f32) + ldf(x, base + lane, f32);
    float v1 = ldf(out, base + lane + 64, f32) + ldf(x, base + lane + 64, f32);
    float s = v0 + v1, ss = v0 * v0 + v1 * v1;
#pragma unroll
    for (int off = 32; off; off >>= 1) {
        s += __shfl_xor(s, off, 64);
        ss += __shfl_xor(ss, off, 64);
    }
    float mu = s * (1.0f / ND);
    float var = ss * (1.0f / ND) - mu * mu;
    float rs = rsqrtf(var + 1e-6f);
    float o0 = (v0 - mu) * rs * ldf(g, lane, f32) + ldf(be, lane, f32);
    float o1 = (v1 - mu) * rs * ldf(g, lane + 64, f32) + ldf(be, lane + 64, f32);
    stf(out, base + lane, f32, o0);
    stf(out, base + lane + 64, f32, o1);
}

// ---------------------------------------------------------------------------
extern "C" void kernel_launch(void* const* d_in, const int* in_sizes, int n_in,
                              void* d_out, int out_size, void* d_ws, size_t ws_size,
                              hipStream_t stream) {
    const void* x = d_in[0];
    const void* mask = d_in[1];
    const int* ei = (const int*)d_in[2];
    const void* ea = d_in[3];
    const void* Wq = d_in[4];
    const void* Wk = d_in[5];
    const void* Wv = d_in[6];
    const void* Wew = d_in[7];
    const void* Web = d_in[8];
    const void* lng = d_in[9];
    const void* lnb = d_in[10];

    char* ws = (char*)d_ws;
    size_t off = 0;
    int* flags = (int*)(ws + off);       off += 256;
    float* wmean = (float*)(ws + off);   off += 1024;
    float* degr = (float*)(ws + off);    off += (size_t)NB * NN * 4;
    float* degc = (float*)(ws + off);    off += (size_t)NB * NN * 4;
    int* rowstart = (int*)(ws + off);    off += (size_t)NB * (NN + 1) * 4 + 512;
    u16* colsG = (u16*)(ws + off);       off += (size_t)NB * NE * 2;
    float* featsG = (float*)(ws + off);  off += (size_t)NB * NE * 4;
    float* featsE = (float*)(ws + off);  off += (size_t)NB * NE * 4;
    u16* WP = (u16*)(ws + off);          off += (size_t)5 * 24 * 64 * 8 * 2;
    const size_t qkv_elems = (size_t)NB * NH * NN * NDK;
    u16* qw = (u16*)(ws + off);          off += qkv_elems * 2;
    u16* kw = (u16*)(ws + off);          off += qkv_elems * 2;
    u16* vw = (u16*)(ws + off);          off += qkv_elems * 2;  // row-major V
    u16* vt = (u16*)(ws + off);          off += qkv_elems * 2;  // transposed V

    k_detect<<<1, 256, 0, stream>>>((const u16*)x, (const u8*)mask, flags);
    k_wmean<<<129, 64, 0, stream>>>(Wew, Web, flags, wmean);
    k_efeat<<<(NB * NE) / 16, 256, 0, stream>>>(ea, wmean, flags, featsE);
    k_csr<<<NB, 256, 0, stream>>>(ei, featsE, degr, degc, rowstart, colsG, featsG);
    k_packB<<<120, 64, 0, stream>>>(Wq, Wk, Wv, flags, WP);
    k_gemm<<<(NB * NN) / 64, 256, 0, stream>>>(x, degr, degc, WP, flags, qw, kw, vw, vt);
    k_attn<<<dim3(NH, NB), 256, 0, stream>>>(qw, kw, vw, vt, mask, flags, rowstart,
                                             colsG, featsG, d_out);
    k_ln<<<(NB * NN) / 4, 256, 0, stream>>>(d_out, x, lng, lnb, flags);
}